// Round 4
// baseline (364.315 us; speedup 1.0000x reference)
//
#include <hip/hip_runtime.h>
#include <hip/hip_bf16.h>
#include <cstdint>

#define SEQ 2048
#define NH  16
#define HD  64
#define DM  1024
#define BATCH 2

typedef unsigned short ushort_t;
typedef __attribute__((ext_vector_type(8))) short short8;   // bf16x8 MFMA frag (4 VGPRs)
typedef __attribute__((ext_vector_type(4))) float f32x4;    // fp32x4 accum

__device__ __forceinline__ ushort_t f2bf(float f){
  __hip_bfloat16 h = __float2bfloat16(f);
  return *reinterpret_cast<ushort_t*>(&h);
}

// ---------------- 128x128 GEMM core, fp32 inputs (cvt->bf16 on stage):
// C[m,n] = sum_k A[m,k]*B[n,k], both K-contiguous. 256 thr = 4 waves (2x2 of 64x64),
// BK=32, 16x16x32 bf16 MFMA.
__device__ __forceinline__ void gemm_core_128_f32(
    const float* __restrict__ A, const float* __restrict__ B,
    ushort_t* As, ushort_t* Bs, int m0, int n0, f32x4 acc[4][4])
{
  const int tid  = threadIdx.x;
  const int lane = tid & 63;
  const int wave = tid >> 6;
  const int quad = lane >> 4, l16 = lane & 15;
  const int wm = (wave >> 1) * 64, wn = (wave & 1) * 64;
  for(int k0 = 0; k0 < DM; k0 += 32){
    #pragma unroll
    for(int u = 0; u < 4; u++){
      int idx = tid + u * 256;                // 0..1023
      int row = idx >> 3, seg = idx & 7;      // 128 rows x 8 float4-segs
      float4 av = *reinterpret_cast<const float4*>(&A[(size_t)(m0+row)*DM + k0 + seg*4]);
      float4 bv = *reinterpret_cast<const float4*>(&B[(size_t)(n0+row)*DM + k0 + seg*4]);
      ushort_t at[4] = {f2bf(av.x), f2bf(av.y), f2bf(av.z), f2bf(av.w)};
      ushort_t bt[4] = {f2bf(bv.x), f2bf(bv.y), f2bf(bv.z), f2bf(bv.w)};
      *reinterpret_cast<uint2*>(&As[row*32 + seg*4]) = *reinterpret_cast<const uint2*>(at);
      *reinterpret_cast<uint2*>(&Bs[row*32 + seg*4]) = *reinterpret_cast<const uint2*>(bt);
    }
    __syncthreads();
    short8 af[4], bf[4];
    #pragma unroll
    for(int mt=0;mt<4;mt++) af[mt] = *reinterpret_cast<const short8*>(&As[(wm+mt*16+l16)*32 + quad*8]);
    #pragma unroll
    for(int nt=0;nt<4;nt++) bf[nt] = *reinterpret_cast<const short8*>(&Bs[(wn+nt*16+l16)*32 + quad*8]);
    #pragma unroll
    for(int mt=0;mt<4;mt++)
      #pragma unroll
      for(int nt=0;nt<4;nt++)
        acc[mt][nt] = __builtin_amdgcn_mfma_f32_16x16x32_bf16(af[mt], bf[nt], acc[mt][nt], 0, 0, 0);
    __syncthreads();
  }
}

// ---------------- QKV projection + RoPE (z=0:Q, z=1:K, z=2:V^T). Outputs bf16.
__global__ __launch_bounds__(256) void qkv_gemm_kernel(
    const float* __restrict__ x,
    const float* __restrict__ Wq, const float* __restrict__ Wk,
    const float* __restrict__ Wv,
    ushort_t* __restrict__ Q,    // [B,H,S,D] bf16 (ws; attn overwrites in-place)
    ushort_t* __restrict__ Ko,   // [B,H,S,D] bf16 (d_out scratch)
    ushort_t* __restrict__ Vt)   // [B,H,D,S] bf16 (d_out scratch)
{
  const int z = blockIdx.z;
  const float* W = (z == 0) ? Wq : (z == 1) ? Wk : Wv;
  const int m0 = blockIdx.x * 128;   // over B*S = 4096
  const int n0 = blockIdx.y * 128;   // over DM = 1024

  // Union: GEMM staging (16 KB) then RoPE trig table (32 KB); staging is dead
  // after gemm_core's final barrier.
  __shared__ __align__(16) char smem[32768];
  ushort_t* As  = (ushort_t*)smem;            // 8 KB
  ushort_t* Bs  = (ushort_t*)(smem + 8192);   // 8 KB
  float*   trig = (float*)smem;               // 128 rows * 32 freqs * {cos,sin} = 32 KB

  const int tid  = threadIdx.x;
  const int lane = tid & 63;
  const int wave = tid >> 6;
  const int quad = lane >> 4, l16 = lane & 15;
  const int wm = (wave >> 1) * 64, wn = (wave & 1) * 64;

  f32x4 acc[4][4];
  #pragma unroll
  for(int i=0;i<4;i++)
    #pragma unroll
    for(int j=0;j<4;j++) acc[i][j] = (f32x4){0.f,0.f,0.f,0.f};

  gemm_core_128_f32(x, W, As, Bs, m0, n0, acc);   // ends with __syncthreads()

  // Epilogue. C/D layout: col = l16 (n), row = quad*4 + reg (m).
  if(z < 2){
    // Block-local RoPE trig for rows m0..m0+127 (s = m & 2047), 32 freqs.
    for(int p = tid; p < 128*32; p += 256){
      int i = p >> 5, j = p & 31;
      float invf = exp2f(-(float)j * 0.41524101186092033f);  // 10000^(-j/32)
      float ang  = (float)((m0 + i) & 2047) * invf;
      float sn, cn;
      sincosf(ang, &sn, &cn);
      trig[i*64 + j*2]     = cn;
      trig[i*64 + j*2 + 1] = sn;
    }
    __syncthreads();

    ushort_t* outp = (z == 0) ? Q : Ko;
    #pragma unroll
    for(int nt=0;nt<4;nt++){
      int n  = n0 + wn + nt*16 + l16;
      int h  = n >> 6, dh = n & 63;
      int j  = dh & 31;                       // freq index = dh mod 32
      int outd = (dh >> 1) + (dh & 1) * 32;   // even d=2i -> i ; odd d=2i+1 -> 32+i
      bool even = (dh & 1) == 0;
      #pragma unroll
      for(int mt=0;mt<4;mt++){
        #pragma unroll
        for(int r=0;r<4;r++){
          int m = m0 + wm + mt*16 + quad*4 + r;
          int b = m >> 11, s = m & 2047;
          float v = acc[mt][nt][r];
          float p = __shfl_xor(v, 1);         // partner input dim dh^1 (lane l16^1)
          float cn = trig[(m - m0)*64 + j*2];
          float sn = trig[(m - m0)*64 + j*2 + 1];
          float o = even ? (v * cn - p * sn)   // x1*cos - x2*sin
                         : (p * sn + v * cn);  // x1*sin + x2*cos
          outp[((size_t)(b*NH + h)*SEQ + s)*HD + outd] = f2bf(o);
        }
      }
    }
  } else {
    #pragma unroll
    for(int nt=0;nt<4;nt++){
      int n = n0 + wn + nt*16 + l16;
      int h = n >> 6, dh = n & 63;
      #pragma unroll
      for(int mt=0;mt<4;mt++){
        #pragma unroll
        for(int r=0;r<4;r++){
          int m = m0 + wm + mt*16 + quad*4 + r;
          int b = m >> 11, s = m & 2047;
          Vt[((size_t)(b*NH + h)*HD + dh)*SEQ + s] = f2bf(acc[mt][nt][r]);
        }
      }
    }
  }
}

// ---------------- Flash attention, causal. Block = 64 q rows x (b,h); 4 waves x 16 rows.
// Output written IN-PLACE over this block's own Q tile ([B,H,S,D]): all Q reads
// happen up front, all writes after the last barrier; no other block touches it.
__global__ __launch_bounds__(256) void attn_kernel(
    ushort_t* __restrict__ Qbuf, const ushort_t* __restrict__ K,
    const ushort_t* __restrict__ Vt)
{
  const int bh = blockIdx.x;            // 0..31
  const int qb = blockIdx.y;            // 0..31
  const int tid  = threadIdx.x;
  const int lane = tid & 63;
  const int wave = tid >> 6;
  const int quad = lane >> 4, l16 = lane & 15;
  const int q0 = qb * 64;

  ushort_t*       Qp = Qbuf + (size_t)bh * SEQ * HD;
  const ushort_t* Kp = K    + (size_t)bh * SEQ * HD;
  const ushort_t* Vp = Vt   + (size_t)bh * HD * SEQ;

  // Q fragments (A-operand): lane holds Q[q0+wave*16+l16][kk*32+quad*8 ..+8]
  const int qrow_a = q0 + wave*16 + l16;
  short8 qf[2];
  #pragma unroll
  for(int kk=0;kk<2;kk++)
    qf[kk] = *reinterpret_cast<const short8*>(&Qp[(size_t)qrow_a*HD + kk*32 + quad*8]);

  __shared__ __align__(16) ushort_t Plds[4][16*72];   // per-wave P tile, pitch 72

  f32x4 oacc[4];
  #pragma unroll
  for(int dt=0;dt<4;dt++) oacc[dt] = (f32x4){0.f,0.f,0.f,0.f};
  float mrow[4], lrow[4];
  #pragma unroll
  for(int r=0;r<4;r++){ mrow[r] = -1e30f; lrow[r] = 0.f; }

  const int qrow_c = q0 + wave*16 + quad*4;   // +r gives this lane's C-layout rows
  const int ntiles = qb + 1;                  // block-uniform -> in-loop barriers legal

  for(int t=0;t<ntiles;t++){
    const int kv0 = t * 64;
    short8 kf[4][2];
    #pragma unroll
    for(int nt=0;nt<4;nt++)
      #pragma unroll
      for(int kk=0;kk<2;kk++)
        kf[nt][kk] = *reinterpret_cast<const short8*>(&Kp[(size_t)(kv0 + nt*16 + l16)*HD + kk*32 + quad*8]);

    f32x4 sacc[4];
    #pragma unroll
    for(int nt=0;nt<4;nt++) sacc[nt] = (f32x4){0.f,0.f,0.f,0.f};
    #pragma unroll
    for(int kk=0;kk<2;kk++)
      #pragma unroll
      for(int nt=0;nt<4;nt++)
        sacc[nt] = __builtin_amdgcn_mfma_f32_16x16x32_bf16(qf[kk], kf[nt][kk], sacc[nt], 0,0,0);

    // scale + causal mask (only diagonal tile can violate)
    float pv[4][4];
    #pragma unroll
    for(int nt=0;nt<4;nt++){
      int kv = kv0 + nt*16 + l16;
      #pragma unroll
      for(int r=0;r<4;r++){
        float sv = sacc[nt][r] * 0.125f;
        if(t == qb && kv > qrow_c + r) sv = -1e30f;
        pv[nt][r] = sv;
      }
    }
    // online softmax (row quad*4+r lives across the 16 lanes of this quad)
    #pragma unroll
    for(int r=0;r<4;r++){
      float m = fmaxf(fmaxf(pv[0][r],pv[1][r]), fmaxf(pv[2][r],pv[3][r]));
      m = fmaxf(m, __shfl_xor(m,1));
      m = fmaxf(m, __shfl_xor(m,2));
      m = fmaxf(m, __shfl_xor(m,4));
      m = fmaxf(m, __shfl_xor(m,8));
      float mnew = fmaxf(mrow[r], m);
      float alpha = __expf(mrow[r] - mnew);
      mrow[r] = mnew;
      float lsum = 0.f;
      #pragma unroll
      for(int nt=0;nt<4;nt++){
        float p = __expf(pv[nt][r] - mnew);
        pv[nt][r] = p;
        lsum += p;
      }
      lsum += __shfl_xor(lsum,1);
      lsum += __shfl_xor(lsum,2);
      lsum += __shfl_xor(lsum,4);
      lsum += __shfl_xor(lsum,8);
      lrow[r] = lrow[r] * alpha + lsum;
      #pragma unroll
      for(int dt=0;dt<4;dt++) oacc[dt][r] *= alpha;
    }

    // P (C-layout) -> LDS -> A-layout, fenced both ways.
    __syncthreads();
    ushort_t* pl = &Plds[wave][0];
    #pragma unroll
    for(int nt=0;nt<4;nt++)
      #pragma unroll
      for(int r=0;r<4;r++)
        pl[(quad*4 + r)*72 + nt*16 + l16] = f2bf(pv[nt][r]);
    __syncthreads();

    short8 vf[4][2];
    #pragma unroll
    for(int dt=0;dt<4;dt++)
      #pragma unroll
      for(int kk=0;kk<2;kk++)
        vf[dt][kk] = *reinterpret_cast<const short8*>(&Vp[(size_t)(dt*16 + l16)*SEQ + kv0 + kk*32 + quad*8]);

    #pragma unroll
    for(int kk=0;kk<2;kk++){
      short8 pf = *reinterpret_cast<const short8*>(&pl[l16*72 + kk*32 + quad*8]);
      #pragma unroll
      for(int dt=0;dt<4;dt++)
        oacc[dt] = __builtin_amdgcn_mfma_f32_16x16x32_bf16(pf, vf[dt][kk], oacc[dt], 0,0,0);
    }
  }

  // epilogue: write attention output in-place over this block's Q tile, bf16.
  #pragma unroll
  for(int r=0;r<4;r++){
    float inv = 1.0f / lrow[r];
    int s = qrow_c + r;
    #pragma unroll
    for(int dt=0;dt<4;dt++){
      float o = oacc[dt][r] * inv;
      Qp[(size_t)s*HD + dt*16 + l16] = f2bf(o);
    }
  }
}

// ---------------- Output projection: out[m,n] = sum_k ctx[m,k]*Wo[n,k], fp32 out.
// ctx is bf16 [B,H,S,D]; a 32-wide k-chunk never crosses a head boundary.
__global__ __launch_bounds__(256) void out_proj_kernel(
    const ushort_t* __restrict__ ctx, const float* __restrict__ Wo,
    float* __restrict__ out)
{
  const int m0 = blockIdx.x * 128;
  const int n0 = blockIdx.y * 128;
  __shared__ __align__(16) ushort_t As[128*32];
  __shared__ __align__(16) ushort_t Bs[128*32];
  const int tid  = threadIdx.x;
  const int lane = tid & 63;
  const int wave = tid >> 6;
  const int quad = lane >> 4, l16 = lane & 15;
  const int wm = (wave >> 1) * 64, wn = (wave & 1) * 64;

  f32x4 acc[4][4];
  #pragma unroll
  for(int i=0;i<4;i++)
    #pragma unroll
    for(int j=0;j<4;j++) acc[i][j] = (f32x4){0.f,0.f,0.f,0.f};

  for(int k0 = 0; k0 < DM; k0 += 32){
    const int head = k0 >> 6, off = k0 & 63;
    // A: bf16 gather from ctx (16B segs)
    #pragma unroll
    for(int u = 0; u < 2; u++){
      int idx = tid + u * 256;                // 0..511
      int row = idx >> 2, seg = idx & 3;
      int m = m0 + row, b = m >> 11, s = m & 2047;
      *reinterpret_cast<uint4*>(&As[row*32 + seg*8]) =
        *reinterpret_cast<const uint4*>(&ctx[((size_t)(b*NH + head)*SEQ + s)*HD + off + seg*8]);
    }
    // B: fp32 Wo -> cvt -> bf16 (8B segs)
    #pragma unroll
    for(int u = 0; u < 4; u++){
      int idx = tid + u * 256;                // 0..1023
      int row = idx >> 3, seg = idx & 7;
      float4 bv = *reinterpret_cast<const float4*>(&Wo[(size_t)(n0+row)*DM + k0 + seg*4]);
      ushort_t bt[4] = {f2bf(bv.x), f2bf(bv.y), f2bf(bv.z), f2bf(bv.w)};
      *reinterpret_cast<uint2*>(&Bs[row*32 + seg*4]) = *reinterpret_cast<const uint2*>(bt);
    }
    __syncthreads();
    short8 af[4], bf[4];
    #pragma unroll
    for(int mt=0;mt<4;mt++) af[mt] = *reinterpret_cast<const short8*>(&As[(wm+mt*16+l16)*32 + quad*8]);
    #pragma unroll
    for(int nt=0;nt<4;nt++) bf[nt] = *reinterpret_cast<const short8*>(&Bs[(wn+nt*16+l16)*32 + quad*8]);
    #pragma unroll
    for(int mt=0;mt<4;mt++)
      #pragma unroll
      for(int nt=0;nt<4;nt++)
        acc[mt][nt] = __builtin_amdgcn_mfma_f32_16x16x32_bf16(af[mt], bf[nt], acc[mt][nt], 0, 0, 0);
    __syncthreads();
  }

  #pragma unroll
  for(int mt=0;mt<4;mt++)
    #pragma unroll
    for(int nt=0;nt<4;nt++)
      #pragma unroll
      for(int r=0;r<4;r++){
        int m = m0 + wm + mt*16 + quad*4 + r;
        int n = n0 + wn + nt*16 + l16;
        out[(size_t)m*DM + n] = acc[mt][nt][r];
      }
}

extern "C" void kernel_launch(void* const* d_in, const int* in_sizes, int n_in,
                              void* d_out, int out_size, void* d_ws, size_t ws_size,
                              hipStream_t stream) {
  // Inputs are float32 per the reference (round-3 diagnosis: bf16 misread -> NaN).
  const float* x  = (const float*)d_in[0];
  const float* Wq = (const float*)d_in[1];
  const float* Wk = (const float*)d_in[2];
  const float* Wv = (const float*)d_in[3];
  const float* Wo = (const float*)d_in[4];
  // d_in[5] = attn_mask (tril int32) — implemented positionally as causal.
  float* out = (float*)d_out;

  // Scratch: d_out is 4M fp32 = 16 MB; stage K (8 MB bf16) + V^T (8 MB bf16)
  // there — both dead before out_proj writes the real fp32 result. ws holds
  // only Q/ctx (8 MB bf16), overwritten in-place by attn.
  ushort_t* Qb = (ushort_t*)d_ws;                          // 8 MB: Q -> ctx in-place
  ushort_t* Kb = (ushort_t*)d_out;                         // 8 MB: K scratch
  ushort_t* Vt = (ushort_t*)d_out + (size_t)BATCH*NH*SEQ*HD;  // 8 MB: V^T scratch

  dim3 g1(32, 8, 3);   // 4096/128 x 1024/128 x {Q,K,V}
  qkv_gemm_kernel<<<g1, 256, 0, stream>>>(x, Wq, Wk, Wv, Qb, Kb, Vt);

  dim3 g2(32, 32);     // (bh, qblock)
  attn_kernel<<<g2, 256, 0, stream>>>(Qb, Kb, Vt);

  dim3 g3(32, 8);
  out_proj_kernel<<<g3, 256, 0, stream>>>(Qb, Wo, out);
}

// Round 5
// 342.362 us; speedup vs baseline: 1.0641x; 1.0641x over previous
//
#include <hip/hip_runtime.h>
#include <hip/hip_bf16.h>
#include <cstdint>

#define SEQ 2048
#define NH  16
#define HD  64
#define DM  1024
#define BATCH 2

typedef unsigned short ushort_t;
typedef __attribute__((ext_vector_type(8))) short short8;   // bf16x8 MFMA frag (4 VGPRs)
typedef __attribute__((ext_vector_type(4))) float f32x4;    // fp32x4 accum

__device__ __forceinline__ ushort_t f2bf(float f){
  __hip_bfloat16 h = __float2bfloat16(f);
  return *reinterpret_cast<ushort_t*>(&h);
}

// ---------------- 128x128 GEMM core, fp32 inputs (cvt->bf16 on stage):
// C[m,n] = sum_k A[m,k]*B[n,k], both K-contiguous. 256 thr = 4 waves (2x2 of 64x64),
// BK=32, 16x16x32 bf16 MFMA.
__device__ __forceinline__ void gemm_core_128_f32(
    const float* __restrict__ A, const float* __restrict__ B,
    ushort_t* As, ushort_t* Bs, int m0, int n0, f32x4 acc[4][4])
{
  const int tid  = threadIdx.x;
  const int lane = tid & 63;
  const int wave = tid >> 6;
  const int quad = lane >> 4, l16 = lane & 15;
  const int wm = (wave >> 1) * 64, wn = (wave & 1) * 64;
  for(int k0 = 0; k0 < DM; k0 += 32){
    #pragma unroll
    for(int u = 0; u < 4; u++){
      int idx = tid + u * 256;                // 0..1023
      int row = idx >> 3, seg = idx & 7;      // 128 rows x 8 float4-segs
      float4 av = *reinterpret_cast<const float4*>(&A[(size_t)(m0+row)*DM + k0 + seg*4]);
      float4 bv = *reinterpret_cast<const float4*>(&B[(size_t)(n0+row)*DM + k0 + seg*4]);
      ushort_t at[4] = {f2bf(av.x), f2bf(av.y), f2bf(av.z), f2bf(av.w)};
      ushort_t bt[4] = {f2bf(bv.x), f2bf(bv.y), f2bf(bv.z), f2bf(bv.w)};
      *reinterpret_cast<uint2*>(&As[row*32 + seg*4]) = *reinterpret_cast<const uint2*>(at);
      *reinterpret_cast<uint2*>(&Bs[row*32 + seg*4]) = *reinterpret_cast<const uint2*>(bt);
    }
    __syncthreads();
    short8 af[4], bf[4];
    #pragma unroll
    for(int mt=0;mt<4;mt++) af[mt] = *reinterpret_cast<const short8*>(&As[(wm+mt*16+l16)*32 + quad*8]);
    #pragma unroll
    for(int nt=0;nt<4;nt++) bf[nt] = *reinterpret_cast<const short8*>(&Bs[(wn+nt*16+l16)*32 + quad*8]);
    #pragma unroll
    for(int mt=0;mt<4;mt++)
      #pragma unroll
      for(int nt=0;nt<4;nt++)
        acc[mt][nt] = __builtin_amdgcn_mfma_f32_16x16x32_bf16(af[mt], bf[nt], acc[mt][nt], 0, 0, 0);
    __syncthreads();
  }
}

// ---------------- QKV projection + RoPE (z=0:Q, z=1:K, z=2:V^T). Outputs bf16.
__global__ __launch_bounds__(256) void qkv_gemm_kernel(
    const float* __restrict__ x,
    const float* __restrict__ Wq, const float* __restrict__ Wk,
    const float* __restrict__ Wv,
    ushort_t* __restrict__ Q,    // [B,H,S,D] bf16 (ws; attn overwrites in-place)
    ushort_t* __restrict__ Ko,   // [B,H,S,D] bf16 (d_out scratch)
    ushort_t* __restrict__ Vt)   // [B,H,D,S] bf16 (d_out scratch)
{
  const int z = blockIdx.z;
  const float* W = (z == 0) ? Wq : (z == 1) ? Wk : Wv;
  const int m0 = blockIdx.x * 128;   // over B*S = 4096
  const int n0 = blockIdx.y * 128;   // over DM = 1024

  __shared__ __align__(16) char smem[32768];
  ushort_t* As  = (ushort_t*)smem;            // 8 KB
  ushort_t* Bs  = (ushort_t*)(smem + 8192);   // 8 KB
  float*   trig = (float*)smem;               // 128 rows * 32 freqs * {cos,sin} = 32 KB

  const int tid  = threadIdx.x;
  const int lane = tid & 63;
  const int wave = tid >> 6;
  const int quad = lane >> 4, l16 = lane & 15;
  const int wm = (wave >> 1) * 64, wn = (wave & 1) * 64;

  f32x4 acc[4][4];
  #pragma unroll
  for(int i=0;i<4;i++)
    #pragma unroll
    for(int j=0;j<4;j++) acc[i][j] = (f32x4){0.f,0.f,0.f,0.f};

  gemm_core_128_f32(x, W, As, Bs, m0, n0, acc);   // ends with __syncthreads()

  // Epilogue. C/D layout: col = l16 (n), row = quad*4 + reg (m).
  if(z < 2){
    for(int p = tid; p < 128*32; p += 256){
      int i = p >> 5, j = p & 31;
      float invf = exp2f(-(float)j * 0.41524101186092033f);  // 10000^(-j/32)
      float ang  = (float)((m0 + i) & 2047) * invf;
      float sn, cn;
      sincosf(ang, &sn, &cn);
      trig[i*64 + j*2]     = cn;
      trig[i*64 + j*2 + 1] = sn;
    }
    __syncthreads();

    ushort_t* outp = (z == 0) ? Q : Ko;
    #pragma unroll
    for(int nt=0;nt<4;nt++){
      int n  = n0 + wn + nt*16 + l16;
      int h  = n >> 6, dh = n & 63;
      int j  = dh & 31;                       // freq index = dh mod 32
      int outd = (dh >> 1) + (dh & 1) * 32;   // even d=2i -> i ; odd d=2i+1 -> 32+i
      bool even = (dh & 1) == 0;
      #pragma unroll
      for(int mt=0;mt<4;mt++){
        #pragma unroll
        for(int r=0;r<4;r++){
          int m = m0 + wm + mt*16 + quad*4 + r;
          int b = m >> 11, s = m & 2047;
          float v = acc[mt][nt][r];
          float p = __shfl_xor(v, 1);         // partner input dim dh^1 (lane l16^1)
          float cn = trig[(m - m0)*64 + j*2];
          float sn = trig[(m - m0)*64 + j*2 + 1];
          float o = even ? (v * cn - p * sn)   // x1*cos - x2*sin
                         : (p * sn + v * cn);  // x1*sin + x2*cos
          outp[((size_t)(b*NH + h)*SEQ + s)*HD + outd] = f2bf(o);
        }
      }
    }
  } else {
    #pragma unroll
    for(int nt=0;nt<4;nt++){
      int n = n0 + wn + nt*16 + l16;
      int h = n >> 6, dh = n & 63;
      #pragma unroll
      for(int mt=0;mt<4;mt++){
        #pragma unroll
        for(int r=0;r<4;r++){
          int m = m0 + wm + mt*16 + quad*4 + r;
          int b = m >> 11, s = m & 2047;
          Vt[((size_t)(b*NH + h)*HD + dh)*SEQ + s] = f2bf(acc[mt][nt][r]);
        }
      }
    }
  }
}

// ---------------- Flash attention, causal — wave-decoupled + statically balanced.
// Each WAVE owns one 16-row q-strip; no __syncthreads anywhere (per-wave LDS
// region + same-wave DS ordering + explicit lgkmcnt fences). Block i of each bh
// runs strips {2i, 2i+1, 126-2i, 127-2i}: per-block tile count == 66 for all i.
__global__ __launch_bounds__(256) void attn_kernel(
    ushort_t* __restrict__ Qbuf, const ushort_t* __restrict__ K,
    const ushort_t* __restrict__ Vt)
{
  const int bh = blockIdx.x;            // 0..31
  const int i  = blockIdx.y;            // 0..31
  const int tid  = threadIdx.x;
  const int lane = tid & 63;
  const int wave = tid >> 6;
  const int quad = lane >> 4, l16 = lane & 15;

  const int strip = (wave == 0) ? 2*i : (wave == 1) ? 2*i+1
                  : (wave == 2) ? 126 - 2*i : 127 - 2*i;   // 0..127
  const int q0   = strip * 16;
  const int diag = strip >> 2;          // index of this strip's diagonal 64-kv tile

  ushort_t*       Qp = Qbuf + (size_t)bh * SEQ * HD;
  const ushort_t* Kp = K    + (size_t)bh * SEQ * HD;
  const ushort_t* Vp = Vt   + (size_t)bh * HD * SEQ;

  // Q fragment (A-operand): lane holds Q[q0+l16][kk*32+quad*8 ..+8]
  short8 qf[2];
  #pragma unroll
  for(int kk=0;kk<2;kk++)
    qf[kk] = *reinterpret_cast<const short8*>(&Qp[(size_t)(q0 + l16)*HD + kk*32 + quad*8]);

  __shared__ __align__(16) ushort_t Plds[4][16*72];   // per-wave P tile, pitch 72
  ushort_t* pl = &Plds[wave][0];

  f32x4 oacc[4];
  #pragma unroll
  for(int dt=0;dt<4;dt++) oacc[dt] = (f32x4){0.f,0.f,0.f,0.f};
  float mrow[4], lrow[4];
  #pragma unroll
  for(int r=0;r<4;r++){ mrow[r] = -1e30f; lrow[r] = 0.f; }
  const int qrow_c = q0 + quad*4;       // +r gives this lane's C-layout rows

  // K fragments for tile 0 (B-operand, K-contiguous), prefetched
  short8 kf[4][2];
  #pragma unroll
  for(int nt=0;nt<4;nt++)
    #pragma unroll
    for(int kk=0;kk<2;kk++)
      kf[nt][kk] = *reinterpret_cast<const short8*>(&Kp[(size_t)(nt*16 + l16)*HD + kk*32 + quad*8]);

  for(int t = 0; t <= diag; t++){
    const int kv0 = t * 64;
    const bool is_diag = (t == diag);   // wave-uniform

    f32x4 sacc[4];
    #pragma unroll
    for(int nt=0;nt<4;nt++) sacc[nt] = (f32x4){0.f,0.f,0.f,0.f};
    #pragma unroll
    for(int kk=0;kk<2;kk++)
      #pragma unroll
      for(int nt=0;nt<4;nt++)
        sacc[nt] = __builtin_amdgcn_mfma_f32_16x16x32_bf16(qf[kk], kf[nt][kk], sacc[nt], 0,0,0);

    // Prefetch next K tile + this tile's V^T while softmax runs (overlaps latency)
    short8 kn[4][2];
    if(!is_diag){
      #pragma unroll
      for(int nt=0;nt<4;nt++)
        #pragma unroll
        for(int kk=0;kk<2;kk++)
          kn[nt][kk] = *reinterpret_cast<const short8*>(&Kp[(size_t)(kv0 + 64 + nt*16 + l16)*HD + kk*32 + quad*8]);
    }
    short8 vf[4][2];
    #pragma unroll
    for(int dt=0;dt<4;dt++)
      #pragma unroll
      for(int kk=0;kk<2;kk++)
        vf[dt][kk] = *reinterpret_cast<const short8*>(&Vp[(size_t)(dt*16 + l16)*SEQ + kv0 + kk*32 + quad*8]);

    // scale + causal mask (diagonal tile only)
    float pv[4][4];
    if(is_diag){
      #pragma unroll
      for(int nt=0;nt<4;nt++){
        int kv = kv0 + nt*16 + l16;
        #pragma unroll
        for(int r=0;r<4;r++){
          float sv = sacc[nt][r] * 0.125f;
          pv[nt][r] = (kv > qrow_c + r) ? -1e30f : sv;
        }
      }
    } else {
      #pragma unroll
      for(int nt=0;nt<4;nt++)
        #pragma unroll
        for(int r=0;r<4;r++)
          pv[nt][r] = sacc[nt][r] * 0.125f;
    }

    // online softmax (row quad*4+r lives across the 16 lanes of this quad)
    #pragma unroll
    for(int r=0;r<4;r++){
      float m = fmaxf(fmaxf(pv[0][r],pv[1][r]), fmaxf(pv[2][r],pv[3][r]));
      m = fmaxf(m, __shfl_xor(m,1));
      m = fmaxf(m, __shfl_xor(m,2));
      m = fmaxf(m, __shfl_xor(m,4));
      m = fmaxf(m, __shfl_xor(m,8));
      float mnew = fmaxf(mrow[r], m);
      float alpha = __expf(mrow[r] - mnew);
      mrow[r] = mnew;
      float lsum = 0.f;
      #pragma unroll
      for(int nt=0;nt<4;nt++){
        float p = __expf(pv[nt][r] - mnew);
        pv[nt][r] = p;
        lsum += p;
      }
      lsum += __shfl_xor(lsum,1);
      lsum += __shfl_xor(lsum,2);
      lsum += __shfl_xor(lsum,4);
      lsum += __shfl_xor(lsum,8);
      lrow[r] = lrow[r] * alpha + lsum;
      #pragma unroll
      for(int dt=0;dt<4;dt++) oacc[dt][r] *= alpha;
    }

    // P (C-layout) -> LDS -> A-layout. Per-wave region; same-wave DS ops run
    // in order on HW. Empty asm = compiler reorder fence (TBAA would otherwise
    // allow hoisting the short8 reads over the ushort writes); waitcnt drains
    // the writes before the dependent reads.
    asm volatile("" ::: "memory");
    #pragma unroll
    for(int nt=0;nt<4;nt++)
      #pragma unroll
      for(int r=0;r<4;r++)
        pl[(quad*4 + r)*72 + nt*16 + l16] = f2bf(pv[nt][r]);
    asm volatile("s_waitcnt lgkmcnt(0)" ::: "memory");

    #pragma unroll
    for(int kk=0;kk<2;kk++){
      short8 pf = *reinterpret_cast<const short8*>(&pl[l16*72 + kk*32 + quad*8]);
      #pragma unroll
      for(int dt=0;dt<4;dt++)
        oacc[dt] = __builtin_amdgcn_mfma_f32_16x16x32_bf16(pf, vf[dt][kk], oacc[dt], 0,0,0);
    }

    if(!is_diag){
      #pragma unroll
      for(int nt=0;nt<4;nt++)
        #pragma unroll
        for(int kk=0;kk<2;kk++)
          kf[nt][kk] = kn[nt][kk];
    }
  }

  // epilogue: write attention output in-place over this wave's own Q strip, bf16.
  #pragma unroll
  for(int r=0;r<4;r++){
    float inv = 1.0f / lrow[r];
    int s = qrow_c + r;
    #pragma unroll
    for(int dt=0;dt<4;dt++){
      float o = oacc[dt][r] * inv;
      Qp[(size_t)s*HD + dt*16 + l16] = f2bf(o);
    }
  }
}

// ---------------- Output projection: out[m,n] = sum_k ctx[m,k]*Wo[n,k], fp32 out.
// ctx is bf16 [B,H,S,D]; a 32-wide k-chunk never crosses a head boundary.
__global__ __launch_bounds__(256) void out_proj_kernel(
    const ushort_t* __restrict__ ctx, const float* __restrict__ Wo,
    float* __restrict__ out)
{
  const int m0 = blockIdx.x * 128;
  const int n0 = blockIdx.y * 128;
  __shared__ __align__(16) ushort_t As[128*32];
  __shared__ __align__(16) ushort_t Bs[128*32];
  const int tid  = threadIdx.x;
  const int lane = tid & 63;
  const int wave = tid >> 6;
  const int quad = lane >> 4, l16 = lane & 15;
  const int wm = (wave >> 1) * 64, wn = (wave & 1) * 64;

  f32x4 acc[4][4];
  #pragma unroll
  for(int i=0;i<4;i++)
    #pragma unroll
    for(int j=0;j<4;j++) acc[i][j] = (f32x4){0.f,0.f,0.f,0.f};

  for(int k0 = 0; k0 < DM; k0 += 32){
    const int head = k0 >> 6, off = k0 & 63;
    #pragma unroll
    for(int u = 0; u < 2; u++){
      int idx = tid + u * 256;                // 0..511
      int row = idx >> 2, seg = idx & 3;
      int m = m0 + row, b = m >> 11, s = m & 2047;
      *reinterpret_cast<uint4*>(&As[row*32 + seg*8]) =
        *reinterpret_cast<const uint4*>(&ctx[((size_t)(b*NH + head)*SEQ + s)*HD + off + seg*8]);
    }
    #pragma unroll
    for(int u = 0; u < 4; u++){
      int idx = tid + u * 256;                // 0..1023
      int row = idx >> 3, seg = idx & 7;
      float4 bv = *reinterpret_cast<const float4*>(&Wo[(size_t)(n0+row)*DM + k0 + seg*4]);
      ushort_t bt[4] = {f2bf(bv.x), f2bf(bv.y), f2bf(bv.z), f2bf(bv.w)};
      *reinterpret_cast<uint2*>(&Bs[row*32 + seg*4]) = *reinterpret_cast<const uint2*>(bt);
    }
    __syncthreads();
    short8 af[4], bf[4];
    #pragma unroll
    for(int mt=0;mt<4;mt++) af[mt] = *reinterpret_cast<const short8*>(&As[(wm+mt*16+l16)*32 + quad*8]);
    #pragma unroll
    for(int nt=0;nt<4;nt++) bf[nt] = *reinterpret_cast<const short8*>(&Bs[(wn+nt*16+l16)*32 + quad*8]);
    #pragma unroll
    for(int mt=0;mt<4;mt++)
      #pragma unroll
      for(int nt=0;nt<4;nt++)
        acc[mt][nt] = __builtin_amdgcn_mfma_f32_16x16x32_bf16(af[mt], bf[nt], acc[mt][nt], 0, 0, 0);
    __syncthreads();
  }

  #pragma unroll
  for(int mt=0;mt<4;mt++)
    #pragma unroll
    for(int nt=0;nt<4;nt++)
      #pragma unroll
      for(int r=0;r<4;r++){
        int m = m0 + wm + mt*16 + quad*4 + r;
        int n = n0 + wn + nt*16 + l16;
        out[(size_t)m*DM + n] = acc[mt][nt][r];
      }
}

extern "C" void kernel_launch(void* const* d_in, const int* in_sizes, int n_in,
                              void* d_out, int out_size, void* d_ws, size_t ws_size,
                              hipStream_t stream) {
  const float* x  = (const float*)d_in[0];
  const float* Wq = (const float*)d_in[1];
  const float* Wk = (const float*)d_in[2];
  const float* Wv = (const float*)d_in[3];
  const float* Wo = (const float*)d_in[4];
  // d_in[5] = attn_mask (tril int32) — implemented positionally as causal.
  float* out = (float*)d_out;

  // Scratch: d_out (16 MB fp32) stages K + V^T bf16 (dead before out_proj
  // writes); ws holds Q/ctx (8 MB bf16), overwritten in-place by attn.
  ushort_t* Qb = (ushort_t*)d_ws;                             // 8 MB: Q -> ctx in-place
  ushort_t* Kb = (ushort_t*)d_out;                            // 8 MB: K scratch
  ushort_t* Vt = (ushort_t*)d_out + (size_t)BATCH*NH*SEQ*HD;  // 8 MB: V^T scratch

  dim3 g1(32, 8, 3);   // 4096/128 x 1024/128 x {Q,K,V}
  qkv_gemm_kernel<<<g1, 256, 0, stream>>>(x, Wq, Wk, Wv, Qb, Kb, Vt);

  dim3 g2(32, 32);     // (bh, block-pair index) — statically balanced strips
  attn_kernel<<<g2, 256, 0, stream>>>(Qb, Kb, Vt);

  dim3 g3(32, 8);
  out_proj_kernel<<<g3, 256, 0, stream>>>(Qb, Wo, out);
}

// Round 6
// 329.461 us; speedup vs baseline: 1.1058x; 1.0392x over previous
//
#include <hip/hip_runtime.h>
#include <hip/hip_bf16.h>
#include <cstdint>

#define SEQ 2048
#define NH  16
#define HD  64
#define DM  1024
#define BATCH 2

typedef unsigned short ushort_t;
typedef __attribute__((ext_vector_type(8))) short short8;   // bf16x8 MFMA frag (4 VGPRs)
typedef __attribute__((ext_vector_type(4))) float f32x4;    // fp32x4 accum

__device__ __forceinline__ ushort_t f2bf(float f){
  __hip_bfloat16 h = __float2bfloat16(f);
  return *reinterpret_cast<ushort_t*>(&h);
}
// RNE bf16 convert without NaN handling (inputs finite by construction)
__device__ __forceinline__ ushort_t f2bf_fast(float f){
  uint32_t u = __float_as_uint(f);
  u += 0x7FFF + ((u >> 16) & 1);
  return (ushort_t)(u >> 16);
}

// ---------------- 128x128 GEMM core, fp32 inputs (cvt->bf16 on stage):
// C[m,n] = sum_k A[m,k]*B[n,k], both K-contiguous. 256 thr = 4 waves (2x2 of 64x64),
// BK=32, 16x16x32 bf16 MFMA.
__device__ __forceinline__ void gemm_core_128_f32(
    const float* __restrict__ A, const float* __restrict__ B,
    ushort_t* As, ushort_t* Bs, int m0, int n0, f32x4 acc[4][4])
{
  const int tid  = threadIdx.x;
  const int lane = tid & 63;
  const int wave = tid >> 6;
  const int quad = lane >> 4, l16 = lane & 15;
  const int wm = (wave >> 1) * 64, wn = (wave & 1) * 64;
  for(int k0 = 0; k0 < DM; k0 += 32){
    #pragma unroll
    for(int u = 0; u < 4; u++){
      int idx = tid + u * 256;                // 0..1023
      int row = idx >> 3, seg = idx & 7;      // 128 rows x 8 float4-segs
      float4 av = *reinterpret_cast<const float4*>(&A[(size_t)(m0+row)*DM + k0 + seg*4]);
      float4 bv = *reinterpret_cast<const float4*>(&B[(size_t)(n0+row)*DM + k0 + seg*4]);
      ushort_t at[4] = {f2bf(av.x), f2bf(av.y), f2bf(av.z), f2bf(av.w)};
      ushort_t bt[4] = {f2bf(bv.x), f2bf(bv.y), f2bf(bv.z), f2bf(bv.w)};
      *reinterpret_cast<uint2*>(&As[row*32 + seg*4]) = *reinterpret_cast<const uint2*>(at);
      *reinterpret_cast<uint2*>(&Bs[row*32 + seg*4]) = *reinterpret_cast<const uint2*>(bt);
    }
    __syncthreads();
    short8 af[4], bf[4];
    #pragma unroll
    for(int mt=0;mt<4;mt++) af[mt] = *reinterpret_cast<const short8*>(&As[(wm+mt*16+l16)*32 + quad*8]);
    #pragma unroll
    for(int nt=0;nt<4;nt++) bf[nt] = *reinterpret_cast<const short8*>(&Bs[(wn+nt*16+l16)*32 + quad*8]);
    #pragma unroll
    for(int mt=0;mt<4;mt++)
      #pragma unroll
      for(int nt=0;nt<4;nt++)
        acc[mt][nt] = __builtin_amdgcn_mfma_f32_16x16x32_bf16(af[mt], bf[nt], acc[mt][nt], 0, 0, 0);
    __syncthreads();
  }
}

// ---------------- QKV projection + RoPE (z=0:Q, z=1:K, z=2:V^T). Outputs bf16.
__global__ __launch_bounds__(256) void qkv_gemm_kernel(
    const float* __restrict__ x,
    const float* __restrict__ Wq, const float* __restrict__ Wk,
    const float* __restrict__ Wv,
    ushort_t* __restrict__ Q,    // [B,H,S,D] bf16 (ws; attn overwrites in-place)
    ushort_t* __restrict__ Ko,   // [B,H,S,D] bf16 (d_out scratch)
    ushort_t* __restrict__ Vt)   // [B,H,D,S] bf16 (d_out scratch)
{
  const int z = blockIdx.z;
  const float* W = (z == 0) ? Wq : (z == 1) ? Wk : Wv;
  const int m0 = blockIdx.x * 128;   // over B*S = 4096
  const int n0 = blockIdx.y * 128;   // over DM = 1024

  __shared__ __align__(16) char smem[32768];
  ushort_t* As  = (ushort_t*)smem;            // 8 KB
  ushort_t* Bs  = (ushort_t*)(smem + 8192);   // 8 KB
  float*   trig = (float*)smem;               // 128 rows * 32 freqs * {cos,sin} = 32 KB

  const int tid  = threadIdx.x;
  const int lane = tid & 63;
  const int wave = tid >> 6;
  const int quad = lane >> 4, l16 = lane & 15;
  const int wm = (wave >> 1) * 64, wn = (wave & 1) * 64;

  f32x4 acc[4][4];
  #pragma unroll
  for(int i=0;i<4;i++)
    #pragma unroll
    for(int j=0;j<4;j++) acc[i][j] = (f32x4){0.f,0.f,0.f,0.f};

  gemm_core_128_f32(x, W, As, Bs, m0, n0, acc);   // ends with __syncthreads()

  // Epilogue. C/D layout: col = l16 (n), row = quad*4 + reg (m).
  if(z < 2){
    for(int p = tid; p < 128*32; p += 256){
      int i = p >> 5, j = p & 31;
      float invf = exp2f(-(float)j * 0.41524101186092033f);  // 10000^(-j/32)
      float ang  = (float)((m0 + i) & 2047) * invf;
      float sn, cn;
      sincosf(ang, &sn, &cn);
      trig[i*64 + j*2]     = cn;
      trig[i*64 + j*2 + 1] = sn;
    }
    __syncthreads();

    ushort_t* outp = (z == 0) ? Q : Ko;
    #pragma unroll
    for(int nt=0;nt<4;nt++){
      int n  = n0 + wn + nt*16 + l16;
      int h  = n >> 6, dh = n & 63;
      int j  = dh & 31;                       // freq index = dh mod 32
      int outd = (dh >> 1) + (dh & 1) * 32;   // even d=2i -> i ; odd d=2i+1 -> 32+i
      bool even = (dh & 1) == 0;
      #pragma unroll
      for(int mt=0;mt<4;mt++){
        #pragma unroll
        for(int r=0;r<4;r++){
          int m = m0 + wm + mt*16 + quad*4 + r;
          int b = m >> 11, s = m & 2047;
          float v = acc[mt][nt][r];
          float p = __shfl_xor(v, 1);         // partner input dim dh^1 (lane l16^1)
          float cn = trig[(m - m0)*64 + j*2];
          float sn = trig[(m - m0)*64 + j*2 + 1];
          float o = even ? (v * cn - p * sn)   // x1*cos - x2*sin
                         : (p * sn + v * cn);  // x1*sin + x2*cos
          outp[((size_t)(b*NH + h)*SEQ + s)*HD + outd] = f2bf(o);
        }
      }
    }
  } else {
    #pragma unroll
    for(int nt=0;nt<4;nt++){
      int n = n0 + wn + nt*16 + l16;
      int h = n >> 6, dh = n & 63;
      #pragma unroll
      for(int mt=0;mt<4;mt++){
        #pragma unroll
        for(int r=0;r<4;r++){
          int m = m0 + wm + mt*16 + quad*4 + r;
          int b = m >> 11, s = m & 2047;
          Vt[((size_t)(b*NH + h)*HD + dh)*SEQ + s] = f2bf(acc[mt][nt][r]);
        }
      }
    }
  }
}

// ---------------- Flash attention, causal — transposed (S^T) orientation.
// Block = 128 threads = 2 waves; wave owns strip-pair (p, 127-p) => exactly 33
// tiles/wave (uniform). S^T = K·Q^T: C-layout col=q=l16, row=kv=quad*4+r, so
// softmax reduces IN-LANE over 16 regs + 2 shuffles (xor16/32); m,l,alpha are
// lane scalars. PV as out^T = V^T·P^T (same V/K/Q/P-read fragment indexing).
__global__ __launch_bounds__(128) void attn_kernel(
    ushort_t* __restrict__ Qbuf, const ushort_t* __restrict__ K,
    const ushort_t* __restrict__ Vt)
{
  const int bh = blockIdx.x;            // 0..31
  const int i  = blockIdx.y;            // 0..31
  const int tid  = threadIdx.x;
  const int lane = tid & 63;
  const int wave = tid >> 6;            // 0..1
  const int quad = lane >> 4, l16 = lane & 15;
  const int pair = i*2 + wave;          // 0..63

  ushort_t*       Qp = Qbuf + (size_t)bh * SEQ * HD;
  const ushort_t* Kp = K    + (size_t)bh * SEQ * HD;
  const ushort_t* Vp = Vt   + (size_t)bh * HD * SEQ;

  __shared__ __align__(16) ushort_t Plds[2][16*72];   // per-wave P tile: 16 q rows x 64 kv (+8 pad)
  ushort_t* pl = &Plds[wave][0];

  #pragma unroll
  for(int pass = 0; pass < 2; pass++){
    const int strip = pass ? (127 - pair) : pair;     // 0..127
    const int q0    = strip * 16;
    const int diag  = strip >> 2;                     // last kv tile index

    // Q fragment (B-operand): lane holds Q[q0+l16][kk*32+quad*8 ..+8]
    short8 qf[2];
    #pragma unroll
    for(int kk=0;kk<2;kk++)
      qf[kk] = *reinterpret_cast<const short8*>(&Qp[(size_t)(q0 + l16)*HD + kk*32 + quad*8]);

    f32x4 oacc[4];
    #pragma unroll
    for(int dt=0;dt<4;dt++) oacc[dt] = (f32x4){0.f,0.f,0.f,0.f};
    float mrow = -1e30f, lrow = 0.f;

    // K fragments for tile 0 (A-operand): lane holds K[kv0+nt*16+l16][kk*32+quad*8..]
    short8 kf[4][2];
    #pragma unroll
    for(int nt=0;nt<4;nt++)
      #pragma unroll
      for(int kk=0;kk<2;kk++)
        kf[nt][kk] = *reinterpret_cast<const short8*>(&Kp[(size_t)(nt*16 + l16)*HD + kk*32 + quad*8]);

    for(int t = 0; t <= diag; t++){
      const int kv0 = t * 64;
      const bool is_diag = (t == diag);   // wave-uniform

      // S^T tile: sacc[nt] C-layout col=q=l16, row=kv=quad*4+r (kv block nt*16)
      f32x4 sacc[4];
      #pragma unroll
      for(int nt=0;nt<4;nt++) sacc[nt] = (f32x4){0.f,0.f,0.f,0.f};
      #pragma unroll
      for(int kk=0;kk<2;kk++)
        #pragma unroll
        for(int nt=0;nt<4;nt++)
          sacc[nt] = __builtin_amdgcn_mfma_f32_16x16x32_bf16(kf[nt][kk], qf[kk], sacc[nt], 0,0,0);

      // Prefetch next K tile + this tile's V^T (overlaps softmax latency)
      short8 kn[4][2];
      if(!is_diag){
        #pragma unroll
        for(int nt=0;nt<4;nt++)
          #pragma unroll
          for(int kk=0;kk<2;kk++)
            kn[nt][kk] = *reinterpret_cast<const short8*>(&Kp[(size_t)(kv0 + 64 + nt*16 + l16)*HD + kk*32 + quad*8]);
      }
      short8 vf[4][2];
      #pragma unroll
      for(int dt=0;dt<4;dt++)
        #pragma unroll
        for(int kk=0;kk<2;kk++)
          vf[dt][kk] = *reinterpret_cast<const short8*>(&Vp[(size_t)(dt*16 + l16)*SEQ + kv0 + kk*32 + quad*8]);

      // scale + causal mask (diag tile only): kv_abs > q_abs
      float pv[4][4];
      const int q_abs = q0 + l16;
      if(is_diag){
        #pragma unroll
        for(int nt=0;nt<4;nt++){
          #pragma unroll
          for(int r=0;r<4;r++){
            int kv_abs = kv0 + nt*16 + quad*4 + r;
            pv[nt][r] = (kv_abs > q_abs) ? -1e30f : sacc[nt][r] * 0.125f;
          }
        }
      } else {
        #pragma unroll
        for(int nt=0;nt<4;nt++)
          #pragma unroll
          for(int r=0;r<4;r++)
            pv[nt][r] = sacc[nt][r] * 0.125f;
      }

      // online softmax — in-lane reduce over 16 kv values, cross-quad via 2 shuffles
      float mx0 = fmaxf(fmaxf(pv[0][0],pv[0][1]), fmaxf(pv[0][2],pv[0][3]));
      float mx1 = fmaxf(fmaxf(pv[1][0],pv[1][1]), fmaxf(pv[1][2],pv[1][3]));
      float mx2 = fmaxf(fmaxf(pv[2][0],pv[2][1]), fmaxf(pv[2][2],pv[2][3]));
      float mx3 = fmaxf(fmaxf(pv[3][0],pv[3][1]), fmaxf(pv[3][2],pv[3][3]));
      float mx  = fmaxf(fmaxf(mx0,mx1), fmaxf(mx2,mx3));
      mx = fmaxf(mx, __shfl_xor(mx, 16));
      mx = fmaxf(mx, __shfl_xor(mx, 32));
      float mnew  = fmaxf(mrow, mx);
      float alpha = __expf(mrow - mnew);
      mrow = mnew;
      float lsum = 0.f;
      #pragma unroll
      for(int nt=0;nt<4;nt++)
        #pragma unroll
        for(int r=0;r<4;r++){
          float p = __expf(pv[nt][r] - mnew);
          pv[nt][r] = p;
          lsum += p;
        }
      lsum += __shfl_xor(lsum, 16);
      lsum += __shfl_xor(lsum, 32);
      lrow = lrow * alpha + lsum;
      #pragma unroll
      for(int dt=0;dt<4;dt++)
        #pragma unroll
        for(int r=0;r<4;r++) oacc[dt][r] *= alpha;

      // P^T -> LDS (row = q = l16, col = kv). r-values contiguous -> packed b64.
      asm volatile("" ::: "memory");
      #pragma unroll
      for(int nt=0;nt<4;nt++){
        uint32_t lo = (uint32_t)f2bf_fast(pv[nt][0]) | ((uint32_t)f2bf_fast(pv[nt][1]) << 16);
        uint32_t hi = (uint32_t)f2bf_fast(pv[nt][2]) | ((uint32_t)f2bf_fast(pv[nt][3]) << 16);
        uint2 pk; pk.x = lo; pk.y = hi;
        *reinterpret_cast<uint2*>(&pl[l16*72 + nt*16 + quad*4]) = pk;
      }
      asm volatile("s_waitcnt lgkmcnt(0)" ::: "memory");

      // PV: out^T = V^T·P^T. A = vf (m=d), B = pf (n=q, k=kv).
      #pragma unroll
      for(int kk=0;kk<2;kk++){
        short8 pf = *reinterpret_cast<const short8*>(&pl[l16*72 + kk*32 + quad*8]);
        #pragma unroll
        for(int dt=0;dt<4;dt++)
          oacc[dt] = __builtin_amdgcn_mfma_f32_16x16x32_bf16(vf[dt][kk], pf, oacc[dt], 0,0,0);
      }

      if(!is_diag){
        #pragma unroll
        for(int nt=0;nt<4;nt++)
          #pragma unroll
          for(int kk=0;kk<2;kk++)
            kf[nt][kk] = kn[nt][kk];
      }
    }

    // epilogue: out^T C-layout col=q=l16, row=d=dt*16+quad*4+r. 4 consecutive d
    // -> packed 8B stores, in-place over this wave's own Q strip.
    float inv = 1.0f / lrow;
    #pragma unroll
    for(int dt=0;dt<4;dt++){
      uint32_t lo = (uint32_t)f2bf_fast(oacc[dt][0] * inv) | ((uint32_t)f2bf_fast(oacc[dt][1] * inv) << 16);
      uint32_t hi = (uint32_t)f2bf_fast(oacc[dt][2] * inv) | ((uint32_t)f2bf_fast(oacc[dt][3] * inv) << 16);
      uint2 pk; pk.x = lo; pk.y = hi;
      *reinterpret_cast<uint2*>(&Qp[(size_t)(q0 + l16)*HD + dt*16 + quad*4]) = pk;
    }
  }
}

// ---------------- Output projection: out[m,n] = sum_k ctx[m,k]*Wo[n,k], fp32 out.
// ctx is bf16 [B,H,S,D]; a 32-wide k-chunk never crosses a head boundary.
__global__ __launch_bounds__(256) void out_proj_kernel(
    const ushort_t* __restrict__ ctx, const float* __restrict__ Wo,
    float* __restrict__ out)
{
  const int m0 = blockIdx.x * 128;
  const int n0 = blockIdx.y * 128;
  __shared__ __align__(16) ushort_t As[128*32];
  __shared__ __align__(16) ushort_t Bs[128*32];
  const int tid  = threadIdx.x;
  const int lane = tid & 63;
  const int wave = tid >> 6;
  const int quad = lane >> 4, l16 = lane & 15;
  const int wm = (wave >> 1) * 64, wn = (wave & 1) * 64;

  f32x4 acc[4][4];
  #pragma unroll
  for(int i=0;i<4;i++)
    #pragma unroll
    for(int j=0;j<4;j++) acc[i][j] = (f32x4){0.f,0.f,0.f,0.f};

  for(int k0 = 0; k0 < DM; k0 += 32){
    const int head = k0 >> 6, off = k0 & 63;
    #pragma unroll
    for(int u = 0; u < 2; u++){
      int idx = tid + u * 256;                // 0..511
      int row = idx >> 2, seg = idx & 3;
      int m = m0 + row, b = m >> 11, s = m & 2047;
      *reinterpret_cast<uint4*>(&As[row*32 + seg*8]) =
        *reinterpret_cast<const uint4*>(&ctx[((size_t)(b*NH + head)*SEQ + s)*HD + off + seg*8]);
    }
    #pragma unroll
    for(int u = 0; u < 4; u++){
      int idx = tid + u * 256;                // 0..1023
      int row = idx >> 3, seg = idx & 7;
      float4 bv = *reinterpret_cast<const float4*>(&Wo[(size_t)(n0+row)*DM + k0 + seg*4]);
      ushort_t bt[4] = {f2bf(bv.x), f2bf(bv.y), f2bf(bv.z), f2bf(bv.w)};
      *reinterpret_cast<uint2*>(&Bs[row*32 + seg*4]) = *reinterpret_cast<const uint2*>(bt);
    }
    __syncthreads();
    short8 af[4], bf[4];
    #pragma unroll
    for(int mt=0;mt<4;mt++) af[mt] = *reinterpret_cast<const short8*>(&As[(wm+mt*16+l16)*32 + quad*8]);
    #pragma unroll
    for(int nt=0;nt<4;nt++) bf[nt] = *reinterpret_cast<const short8*>(&Bs[(wn+nt*16+l16)*32 + quad*8]);
    #pragma unroll
    for(int mt=0;mt<4;mt++)
      #pragma unroll
      for(int nt=0;nt<4;nt++)
        acc[mt][nt] = __builtin_amdgcn_mfma_f32_16x16x32_bf16(af[mt], bf[nt], acc[mt][nt], 0, 0, 0);
    __syncthreads();
  }

  #pragma unroll
  for(int mt=0;mt<4;mt++)
    #pragma unroll
    for(int nt=0;nt<4;nt++)
      #pragma unroll
      for(int r=0;r<4;r++){
        int m = m0 + wm + mt*16 + quad*4 + r;
        int n = n0 + wn + nt*16 + l16;
        out[(size_t)m*DM + n] = acc[mt][nt][r];
      }
}

extern "C" void kernel_launch(void* const* d_in, const int* in_sizes, int n_in,
                              void* d_out, int out_size, void* d_ws, size_t ws_size,
                              hipStream_t stream) {
  const float* x  = (const float*)d_in[0];
  const float* Wq = (const float*)d_in[1];
  const float* Wk = (const float*)d_in[2];
  const float* Wv = (const float*)d_in[3];
  const float* Wo = (const float*)d_in[4];
  // d_in[5] = attn_mask (tril int32) — implemented positionally as causal.
  float* out = (float*)d_out;

  // Scratch: d_out (16 MB fp32) stages K + V^T bf16 (dead before out_proj
  // writes); ws holds Q/ctx (8 MB bf16), overwritten in-place by attn.
  ushort_t* Qb = (ushort_t*)d_ws;                             // 8 MB: Q -> ctx in-place
  ushort_t* Kb = (ushort_t*)d_out;                            // 8 MB: K scratch
  ushort_t* Vt = (ushort_t*)d_out + (size_t)BATCH*NH*SEQ*HD;  // 8 MB: V^T scratch

  dim3 g1(32, 8, 3);   // 4096/128 x 1024/128 x {Q,K,V}
  qkv_gemm_kernel<<<g1, 256, 0, stream>>>(x, Wq, Wk, Wv, Qb, Kb, Vt);

  dim3 g2(32, 32);     // (bh, pair-block) — each wave = strip pair (p,127-p), 33 tiles
  attn_kernel<<<g2, 128, 0, stream>>>(Qb, Kb, Vt);

  dim3 g3(32, 8);
  out_proj_kernel<<<g3, 256, 0, stream>>>(Qb, Wo, out);
}

// Round 7
// 263.113 us; speedup vs baseline: 1.3846x; 1.2522x over previous
//
#include <hip/hip_runtime.h>
#include <hip/hip_bf16.h>
#include <cstdint>

#define SEQ 2048
#define NH  16
#define HD  64
#define DM  1024
#define BATCH 2

typedef unsigned short ushort_t;
typedef __attribute__((ext_vector_type(8))) short short8;   // bf16x8 MFMA frag (4 VGPRs)
typedef __attribute__((ext_vector_type(4))) float f32x4;    // fp32x4 accum

__device__ __forceinline__ ushort_t f2bf(float f){
  __hip_bfloat16 h = __float2bfloat16(f);
  return *reinterpret_cast<ushort_t*>(&h);
}
// RNE bf16 convert without NaN handling (inputs finite by construction)
__device__ __forceinline__ ushort_t f2bf_fast(float f){
  uint32_t u = __float_as_uint(f);
  u += 0x7FFF + ((u >> 16) & 1);
  return (ushort_t)(u >> 16);
}

// ================= pre-convert: fp32 -> bf16 for x and all weights ==========
__global__ __launch_bounds__(256) void cvt_kernel(
    const float* __restrict__ x,  const float* __restrict__ Wq,
    const float* __restrict__ Wk, const float* __restrict__ Wv,
    const float* __restrict__ Wo,
    ushort_t* __restrict__ xb,  ushort_t* __restrict__ wqb,
    ushort_t* __restrict__ wkb, ushort_t* __restrict__ wvb,
    ushort_t* __restrict__ wob)
{
  int f = blockIdx.x * 256 + threadIdx.x;       // 0..2M-1 float4s
  const float* s; ushort_t* d; int off;
  if(f < (1<<20)){ s = x; d = xb; off = f; }
  else{
    int r = f - (1<<20);
    int w = r >> 18;                            // 256K float4s per weight
    off = r & ((1<<18)-1);
    s = (w==0)?Wq:(w==1)?Wk:(w==2)?Wv:Wo;
    d = (w==0)?wqb:(w==1)?wkb:(w==2)?wvb:wob;
  }
  float4 v = *reinterpret_cast<const float4*>(s + (size_t)off*4);
  ushort_t t[4] = {f2bf(v.x), f2bf(v.y), f2bf(v.z), f2bf(v.w)};
  *reinterpret_cast<uint2*>(d + (size_t)off*4) = *reinterpret_cast<const uint2*>(t);
}

// ================= 128x128 GEMM cores (pitch-40 LDS: 2-way banks, free) =====
// bf16 inputs
__device__ __forceinline__ void gemm_core_bf16(
    const ushort_t* __restrict__ A, const ushort_t* __restrict__ B,
    ushort_t* As, ushort_t* Bs, int m0, int n0, f32x4 acc[4][4])
{
  const int tid  = threadIdx.x;
  const int lane = tid & 63;
  const int wave = tid >> 6;
  const int quad = lane >> 4, l16 = lane & 15;
  const int wm = (wave >> 1) * 64, wn = (wave & 1) * 64;
  for(int k0 = 0; k0 < DM; k0 += 32){
    #pragma unroll
    for(int u = 0; u < 2; u++){
      int idx = tid + u * 256;                // 0..511
      int row = idx >> 2, seg = idx & 3;      // 128 rows x 4 x 16B
      *reinterpret_cast<uint4*>(&As[row*40 + seg*8]) =
        *reinterpret_cast<const uint4*>(&A[(size_t)(m0+row)*DM + k0 + seg*8]);
      *reinterpret_cast<uint4*>(&Bs[row*40 + seg*8]) =
        *reinterpret_cast<const uint4*>(&B[(size_t)(n0+row)*DM + k0 + seg*8]);
    }
    __syncthreads();
    short8 af[4], bf[4];
    #pragma unroll
    for(int mt=0;mt<4;mt++) af[mt] = *reinterpret_cast<const short8*>(&As[(wm+mt*16+l16)*40 + quad*8]);
    #pragma unroll
    for(int nt=0;nt<4;nt++) bf[nt] = *reinterpret_cast<const short8*>(&Bs[(wn+nt*16+l16)*40 + quad*8]);
    #pragma unroll
    for(int mt=0;mt<4;mt++)
      #pragma unroll
      for(int nt=0;nt<4;nt++)
        acc[mt][nt] = __builtin_amdgcn_mfma_f32_16x16x32_bf16(af[mt], bf[nt], acc[mt][nt], 0, 0, 0);
    __syncthreads();
  }
}
// fp32 inputs (cvt on stage) — fallback path
__device__ __forceinline__ void gemm_core_f32(
    const float* __restrict__ A, const float* __restrict__ B,
    ushort_t* As, ushort_t* Bs, int m0, int n0, f32x4 acc[4][4])
{
  const int tid  = threadIdx.x;
  const int lane = tid & 63;
  const int wave = tid >> 6;
  const int quad = lane >> 4, l16 = lane & 15;
  const int wm = (wave >> 1) * 64, wn = (wave & 1) * 64;
  for(int k0 = 0; k0 < DM; k0 += 32){
    #pragma unroll
    for(int u = 0; u < 4; u++){
      int idx = tid + u * 256;                // 0..1023
      int row = idx >> 3, seg = idx & 7;      // 128 rows x 8 float4-segs
      float4 av = *reinterpret_cast<const float4*>(&A[(size_t)(m0+row)*DM + k0 + seg*4]);
      float4 bv = *reinterpret_cast<const float4*>(&B[(size_t)(n0+row)*DM + k0 + seg*4]);
      ushort_t at[4] = {f2bf(av.x), f2bf(av.y), f2bf(av.z), f2bf(av.w)};
      ushort_t bt[4] = {f2bf(bv.x), f2bf(bv.y), f2bf(bv.z), f2bf(bv.w)};
      *reinterpret_cast<uint2*>(&As[row*40 + seg*4]) = *reinterpret_cast<const uint2*>(at);
      *reinterpret_cast<uint2*>(&Bs[row*40 + seg*4]) = *reinterpret_cast<const uint2*>(bt);
    }
    __syncthreads();
    short8 af[4], bf[4];
    #pragma unroll
    for(int mt=0;mt<4;mt++) af[mt] = *reinterpret_cast<const short8*>(&As[(wm+mt*16+l16)*40 + quad*8]);
    #pragma unroll
    for(int nt=0;nt<4;nt++) bf[nt] = *reinterpret_cast<const short8*>(&Bs[(wn+nt*16+l16)*40 + quad*8]);
    #pragma unroll
    for(int mt=0;mt<4;mt++)
      #pragma unroll
      for(int nt=0;nt<4;nt++)
        acc[mt][nt] = __builtin_amdgcn_mfma_f32_16x16x32_bf16(af[mt], bf[nt], acc[mt][nt], 0, 0, 0);
    __syncthreads();
  }
}

// ================= QKV epilogue (shared): RoPE for Q/K, transpose for V =====
__device__ __forceinline__ void qkv_epilogue(
    int z, int m0, int n0, f32x4 acc[4][4], float* trig, char* /*smem*/,
    ushort_t* __restrict__ Q, ushort_t* __restrict__ Ko, ushort_t* __restrict__ Vt)
{
  const int tid  = threadIdx.x;
  const int lane = tid & 63;
  const int wave = tid >> 6;
  const int quad = lane >> 4, l16 = lane & 15;
  const int wm = (wave >> 1) * 64, wn = (wave & 1) * 64;
  if(z < 2){
    for(int p = tid; p < 128*32; p += 256){
      int i = p >> 5, j = p & 31;
      float invf = exp2f(-(float)j * 0.41524101186092033f);  // 10000^(-j/32)
      float ang  = (float)((m0 + i) & 2047) * invf;
      float sn, cn;
      sincosf(ang, &sn, &cn);
      trig[i*64 + j*2]     = cn;
      trig[i*64 + j*2 + 1] = sn;
    }
    __syncthreads();
    ushort_t* outp = (z == 0) ? Q : Ko;
    #pragma unroll
    for(int nt=0;nt<4;nt++){
      int n  = n0 + wn + nt*16 + l16;
      int h  = n >> 6, dh = n & 63;
      int j  = dh & 31;
      int outd = (dh >> 1) + (dh & 1) * 32;
      bool even = (dh & 1) == 0;
      #pragma unroll
      for(int mt=0;mt<4;mt++){
        #pragma unroll
        for(int r=0;r<4;r++){
          int m = m0 + wm + mt*16 + quad*4 + r;
          int b = m >> 11, s = m & 2047;
          float v = acc[mt][nt][r];
          float p = __shfl_xor(v, 1);
          float cn = trig[(m - m0)*64 + j*2];
          float sn = trig[(m - m0)*64 + j*2 + 1];
          float o = even ? (v * cn - p * sn) : (p * sn + v * cn);
          outp[((size_t)(b*NH + h)*SEQ + s)*HD + outd] = f2bf(o);
        }
      }
    }
  } else {
    #pragma unroll
    for(int nt=0;nt<4;nt++){
      int n = n0 + wn + nt*16 + l16;
      int h = n >> 6, dh = n & 63;
      #pragma unroll
      for(int mt=0;mt<4;mt++){
        #pragma unroll
        for(int r=0;r<4;r++){
          int m = m0 + wm + mt*16 + quad*4 + r;
          int b = m >> 11, s = m & 2047;
          Vt[((size_t)(b*NH + h)*HD + dh)*SEQ + s] = f2bf(acc[mt][nt][r]);
        }
      }
    }
  }
}

__global__ __launch_bounds__(256) void qkv_bf16_kernel(
    const ushort_t* __restrict__ xb,
    const ushort_t* __restrict__ wqb, const ushort_t* __restrict__ wkb,
    const ushort_t* __restrict__ wvb,
    ushort_t* __restrict__ Q, ushort_t* __restrict__ Ko, ushort_t* __restrict__ Vt)
{
  const int z = blockIdx.z;
  const ushort_t* W = (z == 0) ? wqb : (z == 1) ? wkb : wvb;
  const int m0 = blockIdx.x * 128, n0 = blockIdx.y * 128;
  __shared__ __align__(16) char smem[32768];     // staging (2x10KB) then trig (32KB)
  ushort_t* As = (ushort_t*)smem;
  ushort_t* Bs = (ushort_t*)(smem + 10240);
  f32x4 acc[4][4];
  #pragma unroll
  for(int i=0;i<4;i++)
    #pragma unroll
    for(int j=0;j<4;j++) acc[i][j] = (f32x4){0.f,0.f,0.f,0.f};
  gemm_core_bf16(xb, W, As, Bs, m0, n0, acc);
  qkv_epilogue(z, m0, n0, acc, (float*)smem, smem, Q, Ko, Vt);
}

__global__ __launch_bounds__(256) void qkv_f32_kernel(
    const float* __restrict__ x,
    const float* __restrict__ Wq, const float* __restrict__ Wk,
    const float* __restrict__ Wv,
    ushort_t* __restrict__ Q, ushort_t* __restrict__ Ko, ushort_t* __restrict__ Vt)
{
  const int z = blockIdx.z;
  const float* W = (z == 0) ? Wq : (z == 1) ? Wk : Wv;
  const int m0 = blockIdx.x * 128, n0 = blockIdx.y * 128;
  __shared__ __align__(16) char smem[32768];
  ushort_t* As = (ushort_t*)smem;
  ushort_t* Bs = (ushort_t*)(smem + 10240);
  f32x4 acc[4][4];
  #pragma unroll
  for(int i=0;i<4;i++)
    #pragma unroll
    for(int j=0;j<4;j++) acc[i][j] = (f32x4){0.f,0.f,0.f,0.f};
  gemm_core_f32(x, W, As, Bs, m0, n0, acc);
  qkv_epilogue(z, m0, n0, acc, (float*)smem, smem, Q, Ko, Vt);
}

// ================= Flash attention, causal — coalesced LDS-staged tiles =====
// Block = 4 waves; pass0 strips {4g..4g+3} (diag g), pass1 strips {127-4g-w}
// (diag 31-g): all 4 waves share the SAME kv tile stream both passes; total
// rounds = 33 uniform for every block. K/V tiles staged cooperatively with
// coalesced 1KB wave loads -> LDS (pitch 72: 2-way banks), prefetch 1 ahead.
__global__ __launch_bounds__(256) void attn_kernel(
    ushort_t* __restrict__ Qbuf, const ushort_t* __restrict__ K,
    const ushort_t* __restrict__ Vt)
{
  const int bh = blockIdx.x;            // 0..31
  const int g  = blockIdx.y;            // 0..15
  const int tid  = threadIdx.x;
  const int lane = tid & 63;
  const int wave = tid >> 6;            // 0..3
  const int quad = lane >> 4, l16 = lane & 15;

  ushort_t*       Qp = Qbuf + (size_t)bh * SEQ * HD;
  const ushort_t* Kp = K    + (size_t)bh * SEQ * HD;
  const ushort_t* Vp = Vt   + (size_t)bh * HD * SEQ;

  __shared__ __align__(16) ushort_t Ks[64*72];
  __shared__ __align__(16) ushort_t Vs[64*72];
  __shared__ __align__(16) ushort_t Pl[4][16*72];
  ushort_t* pl = &Pl[wave][0];

  // cooperative staging coords: thread covers 2 chunks per tile per matrix
  const int srow0 = tid >> 3;           // 0..31 (u=0), +32 (u=1)
  const int scol  = (tid & 7) * 8;      // element col (16B chunks)

  #pragma unroll
  for(int pass = 0; pass < 2; pass++){
    const int strip = pass ? (127 - (g*4 + wave)) : (g*4 + wave);
    const int ndiag = pass ? (31 - g) : g;          // == strip>>2 (block-uniform)
    const int q0    = strip * 16;

    short8 qf[2];
    #pragma unroll
    for(int kk=0;kk<2;kk++)
      qf[kk] = *reinterpret_cast<const short8*>(&Qp[(size_t)(q0 + l16)*HD + kk*32 + quad*8]);

    f32x4 oacc[4];
    #pragma unroll
    for(int dt=0;dt<4;dt++) oacc[dt] = (f32x4){0.f,0.f,0.f,0.f};
    float mrow = -1e30f, lrow = 0.f;

    // prefetch tile 0
    uint4 kreg[2], vreg[2];
    #pragma unroll
    for(int u=0;u<2;u++){
      int row = srow0 + u*32;
      kreg[u] = *reinterpret_cast<const uint4*>(&Kp[(size_t)row*HD + scol]);            // K rows contiguous
      vreg[u] = *reinterpret_cast<const uint4*>(&Vp[(size_t)row*SEQ + scol]);           // V^T row=d
    }

    for(int t = 0; t <= ndiag; t++){
      const int kv0 = t * 64;
      const bool is_diag = (t == ndiag);

      __syncthreads();    // WAR: all waves done reading tile t-1 fragments
      #pragma unroll
      for(int u=0;u<2;u++){
        int row = srow0 + u*32;
        *reinterpret_cast<uint4*>(&Ks[row*72 + scol]) = kreg[u];
        *reinterpret_cast<uint4*>(&Vs[row*72 + scol]) = vreg[u];
      }
      __syncthreads();    // RAW: tile t visible

      if(!is_diag){       // prefetch tile t+1 (overlaps all compute below)
        #pragma unroll
        for(int u=0;u<2;u++){
          int row = srow0 + u*32;
          kreg[u] = *reinterpret_cast<const uint4*>(&Kp[(size_t)(kv0 + 64 + row)*HD + scol]);
          vreg[u] = *reinterpret_cast<const uint4*>(&Vp[(size_t)row*SEQ + kv0 + 64 + scol]);
        }
      }

      // fragments from LDS (b128, ~2-way max)
      short8 kf[4][2], vf[4][2];
      #pragma unroll
      for(int nt=0;nt<4;nt++)
        #pragma unroll
        for(int kk=0;kk<2;kk++)
          kf[nt][kk] = *reinterpret_cast<const short8*>(&Ks[(nt*16 + l16)*72 + kk*32 + quad*8]);

      // S^T = K·Q^T : C-layout col=q=l16, row=kv=quad*4+r (block nt*16)
      f32x4 sacc[4];
      #pragma unroll
      for(int nt=0;nt<4;nt++) sacc[nt] = (f32x4){0.f,0.f,0.f,0.f};
      #pragma unroll
      for(int kk=0;kk<2;kk++)
        #pragma unroll
        for(int nt=0;nt<4;nt++)
          sacc[nt] = __builtin_amdgcn_mfma_f32_16x16x32_bf16(kf[nt][kk], qf[kk], sacc[nt], 0,0,0);

      #pragma unroll
      for(int dt=0;dt<4;dt++)
        #pragma unroll
        for(int kk=0;kk<2;kk++)
          vf[dt][kk] = *reinterpret_cast<const short8*>(&Vs[(dt*16 + l16)*72 + kk*32 + quad*8]);

      // scale + causal mask (diag tile only): kv_abs > q_abs
      float pv[4][4];
      const int q_abs = q0 + l16;
      if(is_diag){
        #pragma unroll
        for(int nt=0;nt<4;nt++)
          #pragma unroll
          for(int r=0;r<4;r++){
            int kv_abs = kv0 + nt*16 + quad*4 + r;
            pv[nt][r] = (kv_abs > q_abs) ? -1e30f : sacc[nt][r] * 0.125f;
          }
      } else {
        #pragma unroll
        for(int nt=0;nt<4;nt++)
          #pragma unroll
          for(int r=0;r<4;r++)
            pv[nt][r] = sacc[nt][r] * 0.125f;
      }

      // online softmax — in-lane over 16 kv + 2 cross-quad shuffles
      float mx0 = fmaxf(fmaxf(pv[0][0],pv[0][1]), fmaxf(pv[0][2],pv[0][3]));
      float mx1 = fmaxf(fmaxf(pv[1][0],pv[1][1]), fmaxf(pv[1][2],pv[1][3]));
      float mx2 = fmaxf(fmaxf(pv[2][0],pv[2][1]), fmaxf(pv[2][2],pv[2][3]));
      float mx3 = fmaxf(fmaxf(pv[3][0],pv[3][1]), fmaxf(pv[3][2],pv[3][3]));
      float mx  = fmaxf(fmaxf(mx0,mx1), fmaxf(mx2,mx3));
      mx = fmaxf(mx, __shfl_xor(mx, 16));
      mx = fmaxf(mx, __shfl_xor(mx, 32));
      float mnew  = fmaxf(mrow, mx);
      float alpha = __expf(mrow - mnew);
      mrow = mnew;
      float lsum = 0.f;
      #pragma unroll
      for(int nt=0;nt<4;nt++)
        #pragma unroll
        for(int r=0;r<4;r++){
          float p = __expf(pv[nt][r] - mnew);
          pv[nt][r] = p;
          lsum += p;
        }
      lsum += __shfl_xor(lsum, 16);
      lsum += __shfl_xor(lsum, 32);
      lrow = lrow * alpha + lsum;
      #pragma unroll
      for(int dt=0;dt<4;dt++)
        #pragma unroll
        for(int r=0;r<4;r++) oacc[dt][r] *= alpha;

      // P^T -> per-wave LDS (packed b64; same-wave in-order DS + fences)
      asm volatile("" ::: "memory");
      #pragma unroll
      for(int nt=0;nt<4;nt++){
        uint32_t lo = (uint32_t)f2bf_fast(pv[nt][0]) | ((uint32_t)f2bf_fast(pv[nt][1]) << 16);
        uint32_t hi = (uint32_t)f2bf_fast(pv[nt][2]) | ((uint32_t)f2bf_fast(pv[nt][3]) << 16);
        uint2 pk; pk.x = lo; pk.y = hi;
        *reinterpret_cast<uint2*>(&pl[l16*72 + nt*16 + quad*4]) = pk;
      }
      asm volatile("s_waitcnt lgkmcnt(0)" ::: "memory");

      // PV: out^T = V^T·P^T
      #pragma unroll
      for(int kk=0;kk<2;kk++){
        short8 pf = *reinterpret_cast<const short8*>(&pl[l16*72 + kk*32 + quad*8]);
        #pragma unroll
        for(int dt=0;dt<4;dt++)
          oacc[dt] = __builtin_amdgcn_mfma_f32_16x16x32_bf16(vf[dt][kk], pf, oacc[dt], 0,0,0);
      }
    }

    // epilogue: out^T col=q=l16, row=d — packed 8B stores over own Q strip
    float inv = 1.0f / lrow;
    #pragma unroll
    for(int dt=0;dt<4;dt++){
      uint32_t lo = (uint32_t)f2bf_fast(oacc[dt][0] * inv) | ((uint32_t)f2bf_fast(oacc[dt][1] * inv) << 16);
      uint32_t hi = (uint32_t)f2bf_fast(oacc[dt][2] * inv) | ((uint32_t)f2bf_fast(oacc[dt][3] * inv) << 16);
      uint2 pk; pk.x = lo; pk.y = hi;
      *reinterpret_cast<uint2*>(&Qp[(size_t)(q0 + l16)*HD + dt*16 + quad*4]) = pk;
    }
  }
}

// ================= Output projection =================
__global__ __launch_bounds__(256) void out_proj_bf16_kernel(
    const ushort_t* __restrict__ ctx, const ushort_t* __restrict__ wob,
    float* __restrict__ out)
{
  const int m0 = blockIdx.x * 128, n0 = blockIdx.y * 128;
  __shared__ __align__(16) ushort_t As[128*40];
  __shared__ __align__(16) ushort_t Bs[128*40];
  const int tid  = threadIdx.x;
  const int lane = tid & 63;
  const int wave = tid >> 6;
  const int quad = lane >> 4, l16 = lane & 15;
  const int wm = (wave >> 1) * 64, wn = (wave & 1) * 64;

  f32x4 acc[4][4];
  #pragma unroll
  for(int i=0;i<4;i++)
    #pragma unroll
    for(int j=0;j<4;j++) acc[i][j] = (f32x4){0.f,0.f,0.f,0.f};

  for(int k0 = 0; k0 < DM; k0 += 32){
    const int head = k0 >> 6, off = k0 & 63;
    #pragma unroll
    for(int u = 0; u < 2; u++){
      int idx = tid + u * 256;
      int row = idx >> 2, seg = idx & 3;
      int m = m0 + row, b = m >> 11, s = m & 2047;
      *reinterpret_cast<uint4*>(&As[row*40 + seg*8]) =
        *reinterpret_cast<const uint4*>(&ctx[((size_t)(b*NH + head)*SEQ + s)*HD + off + seg*8]);
      *reinterpret_cast<uint4*>(&Bs[row*40 + seg*8]) =
        *reinterpret_cast<const uint4*>(&wob[(size_t)(n0+row)*DM + k0 + seg*8]);
    }
    __syncthreads();
    short8 af[4], bf[4];
    #pragma unroll
    for(int mt=0;mt<4;mt++) af[mt] = *reinterpret_cast<const short8*>(&As[(wm+mt*16+l16)*40 + quad*8]);
    #pragma unroll
    for(int nt=0;nt<4;nt++) bf[nt] = *reinterpret_cast<const short8*>(&Bs[(wn+nt*16+l16)*40 + quad*8]);
    #pragma unroll
    for(int mt=0;mt<4;mt++)
      #pragma unroll
      for(int nt=0;nt<4;nt++)
        acc[mt][nt] = __builtin_amdgcn_mfma_f32_16x16x32_bf16(af[mt], bf[nt], acc[mt][nt], 0, 0, 0);
    __syncthreads();
  }
  #pragma unroll
  for(int mt=0;mt<4;mt++)
    #pragma unroll
    for(int nt=0;nt<4;nt++)
      #pragma unroll
      for(int r=0;r<4;r++){
        int m = m0 + wm + mt*16 + quad*4 + r;
        int n = n0 + wn + nt*16 + l16;
        out[(size_t)m*DM + n] = acc[mt][nt][r];
      }
}

__global__ __launch_bounds__(256) void out_proj_f32_kernel(
    const ushort_t* __restrict__ ctx, const float* __restrict__ Wo,
    float* __restrict__ out)
{
  const int m0 = blockIdx.x * 128, n0 = blockIdx.y * 128;
  __shared__ __align__(16) ushort_t As[128*40];
  __shared__ __align__(16) ushort_t Bs[128*40];
  const int tid  = threadIdx.x;
  const int lane = tid & 63;
  const int wave = tid >> 6;
  const int quad = lane >> 4, l16 = lane & 15;
  const int wm = (wave >> 1) * 64, wn = (wave & 1) * 64;

  f32x4 acc[4][4];
  #pragma unroll
  for(int i=0;i<4;i++)
    #pragma unroll
    for(int j=0;j<4;j++) acc[i][j] = (f32x4){0.f,0.f,0.f,0.f};

  for(int k0 = 0; k0 < DM; k0 += 32){
    const int head = k0 >> 6, off = k0 & 63;
    #pragma unroll
    for(int u = 0; u < 2; u++){
      int idx = tid + u * 256;
      int row = idx >> 2, seg = idx & 3;
      int m = m0 + row, b = m >> 11, s = m & 2047;
      *reinterpret_cast<uint4*>(&As[row*40 + seg*8]) =
        *reinterpret_cast<const uint4*>(&ctx[((size_t)(b*NH + head)*SEQ + s)*HD + off + seg*8]);
    }
    #pragma unroll
    for(int u = 0; u < 4; u++){
      int idx = tid + u * 256;
      int row = idx >> 3, seg = idx & 7;
      float4 bv = *reinterpret_cast<const float4*>(&Wo[(size_t)(n0+row)*DM + k0 + seg*4]);
      ushort_t bt[4] = {f2bf(bv.x), f2bf(bv.y), f2bf(bv.z), f2bf(bv.w)};
      *reinterpret_cast<uint2*>(&Bs[row*40 + seg*4]) = *reinterpret_cast<const uint2*>(bt);
    }
    __syncthreads();
    short8 af[4], bf[4];
    #pragma unroll
    for(int mt=0;mt<4;mt++) af[mt] = *reinterpret_cast<const short8*>(&As[(wm+mt*16+l16)*40 + quad*8]);
    #pragma unroll
    for(int nt=0;nt<4;nt++) bf[nt] = *reinterpret_cast<const short8*>(&Bs[(wn+nt*16+l16)*40 + quad*8]);
    #pragma unroll
    for(int mt=0;mt<4;mt++)
      #pragma unroll
      for(int nt=0;nt<4;nt++)
        acc[mt][nt] = __builtin_amdgcn_mfma_f32_16x16x32_bf16(af[mt], bf[nt], acc[mt][nt], 0, 0, 0);
    __syncthreads();
  }
  #pragma unroll
  for(int mt=0;mt<4;mt++)
    #pragma unroll
    for(int nt=0;nt<4;nt++)
      #pragma unroll
      for(int r=0;r<4;r++){
        int m = m0 + wm + mt*16 + quad*4 + r;
        int n = n0 + wn + nt*16 + l16;
        out[(size_t)m*DM + n] = acc[mt][nt][r];
      }
}

extern "C" void kernel_launch(void* const* d_in, const int* in_sizes, int n_in,
                              void* d_out, int out_size, void* d_ws, size_t ws_size,
                              hipStream_t stream) {
  const float* x  = (const float*)d_in[0];
  const float* Wq = (const float*)d_in[1];
  const float* Wk = (const float*)d_in[2];
  const float* Wv = (const float*)d_in[3];
  const float* Wo = (const float*)d_in[4];
  // d_in[5] = attn_mask (tril int32) — implemented positionally as causal.
  float* out = (float*)d_out;

  // d_out (16 MB fp32) stages K + V^T bf16 (dead before out_proj writes);
  // ws: Qb (8 MB) always; + optional bf16 copies of x and weights (16 MB).
  char* ws = (char*)d_ws;
  ushort_t* Qb = (ushort_t*)ws;                               // 8 MB: Q -> ctx in-place
  ushort_t* Kb = (ushort_t*)d_out;                            // 8 MB
  ushort_t* Vt = (ushort_t*)d_out + (size_t)BATCH*NH*SEQ*HD;  // 8 MB

  const bool big_ws = ws_size >= (24u << 20);

  if(big_ws){
    ushort_t* xb  = (ushort_t*)(ws + (8u  << 20));            // 8 MB
    ushort_t* wqb = (ushort_t*)(ws + (16u << 20));            // 2 MB each
    ushort_t* wkb = (ushort_t*)(ws + (18u << 20));
    ushort_t* wvb = (ushort_t*)(ws + (20u << 20));
    ushort_t* wob = (ushort_t*)(ws + (22u << 20));
    cvt_kernel<<<8192, 256, 0, stream>>>(x, Wq, Wk, Wv, Wo, xb, wqb, wkb, wvb, wob);
    dim3 g1(32, 8, 3);
    qkv_bf16_kernel<<<g1, 256, 0, stream>>>(xb, wqb, wkb, wvb, Qb, Kb, Vt);
    dim3 g2(32, 16);
    attn_kernel<<<g2, 256, 0, stream>>>(Qb, Kb, Vt);
    dim3 g3(32, 8);
    out_proj_bf16_kernel<<<g3, 256, 0, stream>>>(Qb, wob, out);
  } else {
    dim3 g1(32, 8, 3);
    qkv_f32_kernel<<<g1, 256, 0, stream>>>(x, Wq, Wk, Wv, Qb, Kb, Vt);
    dim3 g2(32, 16);
    attn_kernel<<<g2, 256, 0, stream>>>(Qb, Kb, Vt);
    dim3 g3(32, 8);
    out_proj_f32_kernel<<<g3, 256, 0, stream>>>(Qb, Wo, out);
  }
}